// Round 16
// baseline (1988.887 us; speedup 1.0000x reference)
//
#include <hip/hip_runtime.h>
#include <cstdint>

#define Hn 36
#define G4 144          // 4*H gate rows
#define TT 512
#define BB 2048

__device__ __forceinline__ float sigf(float x) { return 1.0f / (1.0f + __expf(-x)); }
__device__ __forceinline__ float tanh_fast(float x) {
    float e = __expf(2.0f * x);          // exact +-1 limits via over/underflow
    return 1.0f - 2.0f / (e + 1.0f);
}

// array-based dots (fallback kernel only)
#define DOT36(W, H, Z0, Z1, Z2, Z3)                        \
    do {                                                   \
        _Pragma("unroll") for (int _k = 0; _k < 9; ++_k) { \
            float4 hv = *(const float4*)&(H)[_k * 4];      \
            Z0 = fmaf((W)[_k * 4 + 0], hv.x, Z0);          \
            Z1 = fmaf((W)[_k * 4 + 1], hv.y, Z1);          \
            Z2 = fmaf((W)[_k * 4 + 2], hv.z, Z2);          \
            Z3 = fmaf((W)[_k * 4 + 3], hv.w, Z3);          \
        }                                                  \
    } while (0)

#define DOT72(W, H, Z0, Z1, Z2, Z3)                         \
    do {                                                    \
        _Pragma("unroll") for (int _k = 0; _k < 18; ++_k) { \
            float4 hv = *(const float4*)&(H)[_k * 4];       \
            Z0 = fmaf((W)[_k * 4 + 0], hv.x, Z0);           \
            Z1 = fmaf((W)[_k * 4 + 1], hv.y, Z1);           \
            Z2 = fmaf((W)[_k * 4 + 2], hv.z, Z2);           \
            Z3 = fmaf((W)[_k * 4 + 3], hv.w, Z3);           \
        }                                                   \
    } while (0)

// ============ K1: layer-0 REVERSE scan, full batch -> h0r (151 MB ws) ========
// Weights in LDS, quad-major transposed layout: wt[q*144 + row] (float4) ->
// wave lanes (consecutive rows) read consecutive float4s = conflict-free b128.
#define SG1 4
#define NTK1 (SG1 * G4)   // 576
__global__ __launch_bounds__(NTK1) void l0rev_kernel(
    const float* __restrict__ x,
    const float* __restrict__ Wih, const float* __restrict__ Whh,
    const float* __restrict__ bih, const float* __restrict__ bhh,
    float* __restrict__ h0r)
{
    const int tid = threadIdx.x;
    const int cc  = tid / G4;
    const int g   = tid % G4;
    const int b   = blockIdx.x * SG1 + cc;

    __shared__ float4 wt[9 * G4];     // 20.7 KB transposed Whh
    __shared__ float xs[SG1][TT];
    __shared__ float hs[SG1][40];
    __shared__ float zs[SG1][G4];

    for (int i = tid; i < 9 * G4; i += NTK1) {
        int q = i / G4, r = i % G4;
        wt[q * G4 + r] = ((const float4*)(Whh + r * Hn))[q];
    }
    for (int i = g; i < TT; i += G4) xs[cc][i] = x[(size_t)b * TT + i];

    const float wx   = Wih[g];
    const float bias = bih[g] + bhh[g];

    if (g < 40) hs[cc][g] = 0.0f;
    float c = 0.0f;
    __syncthreads();

    float* dst = h0r + (size_t)b * TT * Hn;

    for (int s = 0; s < TT; ++s) {
        const int t = TT - 1 - s;
        float z0 = fmaf(xs[cc][t], wx, bias), z1 = 0.f, z2 = 0.f, z3 = 0.f;
        const float4* hq = (const float4*)&hs[cc][0];
#pragma unroll
        for (int q = 0; q < 9; ++q) {
            float4 w = wt[q * G4 + g];
            float4 h = hq[q];
            z0 = fmaf(w.x, h.x, z0); z1 = fmaf(w.y, h.y, z1);
            z2 = fmaf(w.z, h.z, z2); z3 = fmaf(w.w, h.w, z3);
        }
        zs[cc][g] = (z0 + z1) + (z2 + z3);
        __syncthreads();
        if (g < Hn) {
            float zi = zs[cc][g], zf = zs[cc][g + 36], zg = zs[cc][g + 72], zo = zs[cc][g + 108];
            c = sigf(zf) * c + sigf(zi) * tanh_fast(zg);
            float h = sigf(zo) * tanh_fast(c);
            hs[cc][g] = h;
            dst[(size_t)t * Hn + g] = h;
        }
        __syncthreads();
    }
}

// ====== K2: skewed fusion, 8 chains/block, transposed LDS weight tables ======
// Dot groups: 0:Whh0f.h0f(+x)  1:Wih1f[:, :36].h0f  2:Wih1f[:, 36:].h0r  3:Whh1f.h1
// Thread = (sub: chain half, gp: group, rr: row pair {rr, rr+72}).
// Combine roles (verified r14/r15): tid<288 -> L0 state; tid>=288 -> L1 state + h0r.
#define SG2  8
#define NT2  576
#define NB2  (BB / SG2)   // 256 blocks = 1/CU

__global__ __launch_bounds__(NT2) void fused_fl_kernel(
    const float* __restrict__ x,
    const float* __restrict__ Wih0f, const float* __restrict__ Whh0f,
    const float* __restrict__ bih0f, const float* __restrict__ bhh0f,
    const float* __restrict__ Wih1f, const float* __restrict__ Whh1f,
    const float* __restrict__ bih1f, const float* __restrict__ bhh1f,
    const float* __restrict__ Wih1r,
    const float* __restrict__ bih1r, const float* __restrict__ bhh1r,
    const float* __restrict__ fcW, const float* __restrict__ fcb,
    const float* __restrict__ h0r,
    float* __restrict__ out)
{
    const int tid  = threadIdx.x;
    const int sub  = tid / 288;          // chain half (0: chains 0-3, 1: 4-7)
    const int idx  = tid % 288;
    const int gp   = idx / 72;           // dot group 0..3
    const int rr   = idx % 72;           // row pair: rows rr, rr+72
    const int ch0  = sub * 4;            // first chain of this thread's half
    const int base = blockIdx.x * SG2;
    // combine roles (identical to r14/r15)
    const int ca = tid / Hn;             // L0 chain (tid<288)
    const int ia = tid % Hn;             // L0 unit
    const int ct = tid - 288;            // L1 role index
    const int cb = (ct >= 0) ? ct / Hn : 0;
    const int ib = (ct >= 0) ? ct % Hn : 0;

    __shared__ float4 wt0t[9 * G4];      // Whh0f transposed (20.7 KB)
    __shared__ float4 wt1t[18 * G4];     // Wih1f transposed (41.5 KB)
    __shared__ float4 wt3t[9 * G4];      // Whh1f transposed (20.7 KB)
    __shared__ float xs[SG2][TT + 2];
    __shared__ float h0f[2][SG2][40];
    __shared__ float h0rs[2][SG2][40];
    __shared__ float h1s[SG2][40];
    __shared__ float zF[SG2][G4];
    __shared__ float zL[3][SG2][G4];
    __shared__ float red[SG2][Hn];

    // ---------------- one-time staging (transposed: wt[q*144 + row]) --------
    for (int i = tid; i < 9 * G4; i += NT2) {
        int q = i / G4, r = i % G4;
        wt0t[q * G4 + r] = ((const float4*)(Whh0f + r * Hn))[q];
        wt3t[q * G4 + r] = ((const float4*)(Whh1f + r * Hn))[q];
    }
    for (int i = tid; i < 18 * G4; i += NT2) {
        int q = i / G4, r = i % G4;
        wt1t[q * G4 + r] = ((const float4*)(Wih1f + r * 72))[q];
    }
    for (int i = tid; i < SG2 * (TT + 2); i += NT2) {
        int c = i / (TT + 2), t = i % (TT + 2);
        xs[c][t] = (t < TT) ? x[(size_t)(base + c) * TT + t] : 0.0f;
    }
    for (int i = tid; i < 2 * SG2 * 40; i += NT2) {
        (&h0f[0][0][0])[i] = 0.0f;
        (&h0rs[0][0][0])[i] = 0.0f;
    }
    for (int i = tid; i < SG2 * 40; i += NT2) (&h1s[0][0])[i] = 0.0f;

    const int r0 = rr, r1 = rr + 72;
    const float4* wb4 = (gp == 0) ? wt0t
                      : (gp == 1) ? wt1t
                      : (gp == 2) ? (wt1t + 9 * G4)
                                  : wt3t;
    const float wxA = (gp == 0) ? Wih0f[r0] : 0.0f;
    const float wxB = (gp == 0) ? Wih0f[r1] : 0.0f;
    const float bsA = (gp == 0) ? (bih0f[r0] + bhh0f[r0])
                    : (gp == 3) ? (bih1f[r0] + bhh1f[r0]) : 0.0f;
    const float bsB = (gp == 0) ? (bih0f[r1] + bhh0f[r1])
                    : (gp == 3) ? (bih1f[r1] + bhh1f[r1]) : 0.0f;
    float* zt = (gp == 0) ? &zF[0][0] : &zL[gp - 1][0][0];

    const float* srow = h0r + (size_t)(base + cb) * TT * Hn + ib;   // L1-role h0r stream
    float cs0 = 0.0f, cs1 = 0.0f, rvv = 0.0f;
    __syncthreads();

    // ---- prologue: h0f(0) = step(h=0, x0); stage h0r(0); prefetch h0r(1) ----
    if (gp == 0) {
#pragma unroll
        for (int c = 0; c < 4; ++c) {
            zF[ch0 + c][r0] = fmaf(xs[ch0 + c][0], wxA, bsA);
            zF[ch0 + c][r1] = fmaf(xs[ch0 + c][0], wxB, bsB);
        }
    }
    if (ct >= 0) {
        h0rs[0][cb][ib] = srow[0];
        rvv = srow[Hn];
    }
    __syncthreads();
    if (tid < 288) {
        float zi = zF[ca][ia], zg = zF[ca][ia + 72], zo = zF[ca][ia + 108];
        cs0 = sigf(zi) * tanh_fast(zg);       // c=0 start: forget term vanishes
        h0f[0][ca][ia] = sigf(zo) * tanh_fast(cs0);
    }
    __syncthreads();

    int cur = 0;
    for (int t = 0; t < TT; ++t) {
        float rv2 = (ct >= 0 && t + 2 < TT) ? srow[(size_t)(t + 2) * Hn] : 0.0f;

        const float* hb = (gp <= 1) ? &h0f[cur][ch0][0]
                        : (gp == 2) ? &h0rs[cur][ch0][0] : &h1s[ch0][0];
        // branchless init: wxA/B = 0 and bsA/B in {0, b1} for non-gp0 groups
        float x0v = xs[ch0 + 0][t + 1], x1v = xs[ch0 + 1][t + 1];
        float x2v = xs[ch0 + 2][t + 1], x3v = xs[ch0 + 3][t + 1];
        float a00 = fmaf(x0v, wxA, bsA), a01 = fmaf(x1v, wxA, bsA);
        float a02 = fmaf(x2v, wxA, bsA), a03 = fmaf(x3v, wxA, bsA);
        float a10 = fmaf(x0v, wxB, bsB), a11 = fmaf(x1v, wxB, bsB);
        float a12 = fmaf(x2v, wxB, bsB), a13 = fmaf(x3v, wxB, bsB);

#pragma unroll
        for (int i = 0; i < 9; ++i) {
            float4 w0 = wb4[i * G4 + r0];    // stride-1 across lanes: conflict-free
            float4 w1 = wb4[i * G4 + r1];
            float4 h;
            h = *(const float4*)&hb[0 * 40 + i * 4];
            a00 = fmaf(w0.x, h.x, a00); a00 = fmaf(w0.y, h.y, a00);
            a00 = fmaf(w0.z, h.z, a00); a00 = fmaf(w0.w, h.w, a00);
            a10 = fmaf(w1.x, h.x, a10); a10 = fmaf(w1.y, h.y, a10);
            a10 = fmaf(w1.z, h.z, a10); a10 = fmaf(w1.w, h.w, a10);
            h = *(const float4*)&hb[1 * 40 + i * 4];
            a01 = fmaf(w0.x, h.x, a01); a01 = fmaf(w0.y, h.y, a01);
            a01 = fmaf(w0.z, h.z, a01); a01 = fmaf(w0.w, h.w, a01);
            a11 = fmaf(w1.x, h.x, a11); a11 = fmaf(w1.y, h.y, a11);
            a11 = fmaf(w1.z, h.z, a11); a11 = fmaf(w1.w, h.w, a11);
            h = *(const float4*)&hb[2 * 40 + i * 4];
            a02 = fmaf(w0.x, h.x, a02); a02 = fmaf(w0.y, h.y, a02);
            a02 = fmaf(w0.z, h.z, a02); a02 = fmaf(w0.w, h.w, a02);
            a12 = fmaf(w1.x, h.x, a12); a12 = fmaf(w1.y, h.y, a12);
            a12 = fmaf(w1.z, h.z, a12); a12 = fmaf(w1.w, h.w, a12);
            h = *(const float4*)&hb[3 * 40 + i * 4];
            a03 = fmaf(w0.x, h.x, a03); a03 = fmaf(w0.y, h.y, a03);
            a03 = fmaf(w0.z, h.z, a03); a03 = fmaf(w0.w, h.w, a03);
            a13 = fmaf(w1.x, h.x, a13); a13 = fmaf(w1.y, h.y, a13);
            a13 = fmaf(w1.z, h.z, a13); a13 = fmaf(w1.w, h.w, a13);
        }
        zt[(ch0 + 0) * G4 + r0] = a00; zt[(ch0 + 1) * G4 + r0] = a01;
        zt[(ch0 + 2) * G4 + r0] = a02; zt[(ch0 + 3) * G4 + r0] = a03;
        zt[(ch0 + 0) * G4 + r1] = a10; zt[(ch0 + 1) * G4 + r1] = a11;
        zt[(ch0 + 2) * G4 + r1] = a12; zt[(ch0 + 3) * G4 + r1] = a13;
        __syncthreads();

        if (tid < 288) {                       // L0 combine -> h0f(t+1)
            if (t + 1 < TT) {
                float zi = zF[ca][ia],       zf = zF[ca][ia + 36];
                float zg = zF[ca][ia + 72],  zo = zF[ca][ia + 108];
                cs0 = sigf(zf) * cs0 + sigf(zi) * tanh_fast(zg);
                h0f[cur ^ 1][ca][ia] = sigf(zo) * tanh_fast(cs0);
            }
        } else {                               // L1 combine -> h1(t); stage h0r(t+1)
            float zi = zL[0][cb][ib]       + zL[1][cb][ib]       + zL[2][cb][ib];
            float zf = zL[0][cb][ib + 36]  + zL[1][cb][ib + 36]  + zL[2][cb][ib + 36];
            float zg = zL[0][cb][ib + 72]  + zL[1][cb][ib + 72]  + zL[2][cb][ib + 72];
            float zo = zL[0][cb][ib + 108] + zL[1][cb][ib + 108] + zL[2][cb][ib + 108];
            cs1 = sigf(zf) * cs1 + sigf(zi) * tanh_fast(zg);
            h1s[cb][ib] = sigf(zo) * tanh_fast(cs1);
            if (t + 1 < TT) h0rs[cur ^ 1][cb][ib] = rvv;
        }
        __syncthreads();
        rvv = rv2;
        if (t + 1 < TT) cur ^= 1;
    }

    // ---- tail: L1 reverse single step at t=T-1 (h0=c0=0) + FC ----
    {
        const int gpT = tid / G4, gT = tid % G4;
#pragma unroll
        for (int sub2 = 0; sub2 < 2; ++sub2) {
            const int cc = gpT * 2 + sub2;
            float zR = bih1r[gT] + bhh1r[gT];
            const float* wrq = Wih1r + gT * 72;
#pragma unroll
            for (int k = 0; k < Hn; ++k) zR = fmaf(wrq[k],      h0f[cur][cc][k],  zR);
#pragma unroll
            for (int k = 0; k < Hn; ++k) zR = fmaf(wrq[36 + k], h0rs[cur][cc][k], zR);
            zF[cc][gT] = zR;
        }
    }
    __syncthreads();
    if (tid < 288) {
        float zi = zF[ca][ia], zg = zF[ca][ia + 72], zo = zF[ca][ia + 108];
        float cR = sigf(zi) * tanh_fast(zg);   // c0=0: forget term vanishes
        float hR = sigf(zo) * tanh_fast(cR);
        red[ca][ia] = fcW[36 + ia] * hR + fcW[ia] * h1s[ca][ia];
    }
    __syncthreads();
    if (tid < SG2) {
        float s2 = fcb[0];
        for (int j = 0; j < Hn; ++j) s2 += red[tid][j];
        out[base + tid] = s2;
    }
}

// ================= FALLBACK PATH (zero workspace, ckpt/recompute) ============
__global__ __launch_bounds__(G4, 1) void fused_all_kernel(
    const float* __restrict__ x,
    const float* __restrict__ Wih0f, const float* __restrict__ Whh0f,
    const float* __restrict__ bih0f, const float* __restrict__ bhh0f,
    const float* __restrict__ Wih0r, const float* __restrict__ Whh0r,
    const float* __restrict__ bih0r, const float* __restrict__ bhh0r,
    const float* __restrict__ Wih1f, const float* __restrict__ Whh1f,
    const float* __restrict__ bih1f, const float* __restrict__ bhh1f,
    const float* __restrict__ Wih1r,
    const float* __restrict__ bih1r, const float* __restrict__ bhh1r,
    const float* __restrict__ fcW, const float* __restrict__ fcb,
    float* __restrict__ out)
{
    const int g = threadIdx.x;
    const int b = blockIdx.x;

    __shared__ float xs[TT];
    __shared__ float cbuf[64][Hn];
    __shared__ float ckpt_h[8][Hn], ckpt_c[8][Hn];
    __shared__ float hr[40], h0s[80], hs1[40], zs[G4], red[40];

    for (int i = g; i < TT; i += G4) xs[i] = x[(size_t)b * TT + i];

    float wr[Hn], wf[Hn];
#pragma unroll
    for (int k = 0; k < Hn; ++k) wr[k] = Whh0r[g * Hn + k];
#pragma unroll
    for (int k = 0; k < Hn; ++k) wf[k] = Whh0f[g * Hn + k];
    const float wxr = Wih0r[g], br = bih0r[g] + bhh0r[g];
    const float wxf = Wih0f[g], bf = bih0f[g] + bhh0f[g];
    float w1i[72];
#pragma unroll
    for (int k = 0; k < 72; ++k) w1i[k] = Wih1f[g * 72 + k];
    float w1h[Hn];
#pragma unroll
    for (int k = 0; k < Hn; ++k) w1h[k] = Whh1f[g * Hn + k];
    const float b1 = bih1f[g] + bhh1f[g];

    if (g < Hn) hr[g] = 0.0f;
    float cr = 0.0f;
    __syncthreads();
    for (int s = 0; s < TT; ++s) {
        const int t = TT - 1 - s;
        if ((t & 63) == 63 && g < Hn) { ckpt_h[t >> 6][g] = hr[g]; ckpt_c[t >> 6][g] = cr; }
        float z0 = fmaf(xs[t], wxr, br), z1 = 0.f, z2 = 0.f, z3 = 0.f;
        DOT36(wr, hr, z0, z1, z2, z3);
        zs[g] = (z0 + z1) + (z2 + z3);
        __syncthreads();
        if (g < Hn) {
            float zi = zs[g], zf = zs[g + 36], zg = zs[g + 72], zo = zs[g + 108];
            cr = sigf(zf) * cr + sigf(zi) * tanh_fast(zg);
            hr[g] = sigf(zo) * tanh_fast(cr);
        }
        __syncthreads();
    }

    if (g < Hn) { h0s[g] = 0.0f; hs1[g] = 0.0f; }
    float c0 = 0.0f, c1 = 0.0f;
    __syncthreads();

    for (int m = 0; m < 8; ++m) {
        if (g < Hn) { hr[g] = ckpt_h[m][g]; cr = ckpt_c[m][g]; }
        __syncthreads();
        for (int j = 0; j < 64; ++j) {
            const int t = m * 64 + 63 - j;
            float z0 = fmaf(xs[t], wxr, br), z1 = 0.f, z2 = 0.f, z3 = 0.f;
            DOT36(wr, hr, z0, z1, z2, z3);
            zs[g] = (z0 + z1) + (z2 + z3);
            __syncthreads();
            if (g < Hn) {
                float zi = zs[g], zf = zs[g + 36], zg = zs[g + 72], zo = zs[g + 108];
                cr = sigf(zf) * cr + sigf(zi) * tanh_fast(zg);
                float h = sigf(zo) * tanh_fast(cr);
                hr[g] = h;
                cbuf[t & 63][g] = h;
            }
            __syncthreads();
        }
        for (int j = 0; j < 64; ++j) {
            const int t = m * 64 + j;
            float z0 = fmaf(xs[t], wxf, bf), z1 = 0.f, z2 = 0.f, z3 = 0.f;
            DOT36(wf, h0s, z0, z1, z2, z3);
            zs[g] = (z0 + z1) + (z2 + z3);
            __syncthreads();
            if (g < Hn) {
                float zi = zs[g], zf = zs[g + 36], zg = zs[g + 72], zo = zs[g + 108];
                c0 = sigf(zf) * c0 + sigf(zi) * tanh_fast(zg);
                h0s[g] = sigf(zo) * tanh_fast(c0);
            } else if (g < 72) {
                h0s[g] = cbuf[j][g - 36];
            }
            __syncthreads();
            float y0 = b1, y1 = 0.f, y2 = 0.f, y3 = 0.f;
            DOT72(w1i, h0s, y0, y1, y2, y3);
            DOT36(w1h, hs1, y0, y1, y2, y3);
            zs[g] = (y0 + y1) + (y2 + y3);
            __syncthreads();
            if (g < Hn) {
                float zi = zs[g], zf = zs[g + 36], zg = zs[g + 72], zo = zs[g + 108];
                c1 = sigf(zf) * c1 + sigf(zi) * tanh_fast(zg);
                hs1[g] = sigf(zo) * tanh_fast(c1);
            }
            __syncthreads();
        }
    }

    float zR = bih1r[g] + bhh1r[g];
#pragma unroll
    for (int k = 0; k < 72; ++k) zR = fmaf(Wih1r[g * 72 + k], h0s[k], zR);
    zs[g] = zR;
    __syncthreads();
    if (g < Hn) {
        float zi = zs[g], zg = zs[g + 72], zo = zs[g + 108];
        float c  = sigf(zi) * tanh_fast(zg);
        float hrv = sigf(zo) * tanh_fast(c);
        red[g] = fcW[36 + g] * hrv + fcW[g] * hs1[g];
    }
    __syncthreads();
    if (g == 0) {
        float s = fcb[0];
        for (int j = 0; j < Hn; ++j) s += red[j];
        out[b] = s;
    }
}

extern "C" void kernel_launch(void* const* d_in, const int* in_sizes, int n_in,
                              void* d_out, int out_size, void* d_ws, size_t ws_size,
                              hipStream_t stream)
{
    const float* x     = (const float*)d_in[0];
    const float* Wih0f = (const float*)d_in[1];
    const float* Whh0f = (const float*)d_in[2];
    const float* bih0f = (const float*)d_in[3];
    const float* bhh0f = (const float*)d_in[4];
    const float* Wih0r = (const float*)d_in[5];
    const float* Whh0r = (const float*)d_in[6];
    const float* bih0r = (const float*)d_in[7];
    const float* bhh0r = (const float*)d_in[8];
    const float* Wih1f = (const float*)d_in[9];
    const float* Whh1f = (const float*)d_in[10];
    const float* bih1f = (const float*)d_in[11];
    const float* bhh1f = (const float*)d_in[12];
    const float* Wih1r = (const float*)d_in[13];
    const float* bih1r = (const float*)d_in[15];
    const float* bhh1r = (const float*)d_in[16];
    const float* fcW   = (const float*)d_in[17];
    const float* fcb   = (const float*)d_in[18];

    const size_t need = (size_t)BB * TT * Hn * sizeof(float);   // 151 MB (known-safe)
    if (d_ws != nullptr && ws_size >= need) {
        float* h0r = (float*)d_ws;
        l0rev_kernel<<<BB / SG1, NTK1, 0, stream>>>(x, Wih0r, Whh0r, bih0r, bhh0r, h0r);
        fused_fl_kernel<<<NB2, NT2, 0, stream>>>(
            x, Wih0f, Whh0f, bih0f, bhh0f, Wih1f, Whh1f, bih1f, bhh1f,
            Wih1r, bih1r, bhh1r, fcW, fcb, h0r, (float*)d_out);
    } else {
        fused_all_kernel<<<BB, G4, 0, stream>>>(
            x, Wih0f, Whh0f, bih0f, bhh0f, Wih0r, Whh0r, bih0r, bhh0r,
            Wih1f, Whh1f, bih1f, bhh1f, Wih1r, bih1r, bhh1r, fcW, fcb,
            (float*)d_out);
    }
}

// Round 17
// 1900.708 us; speedup vs baseline: 1.0464x; 1.0464x over previous
//
#include <hip/hip_runtime.h>
#include <cstdint>

#define Hn 36
#define G4 144          // 4*H gate rows
#define TT 512
#define BB 2048

__device__ __forceinline__ float sigf(float x) { return 1.0f / (1.0f + __expf(-x)); }
__device__ __forceinline__ float tanh_fast(float x) {
    float e = __expf(2.0f * x);          // exact +-1 limits via over/underflow
    return 1.0f - 2.0f / (e + 1.0f);
}

// ---- K1 named-register weight quads (r15 l0rev, consistently ~420us) ----
#define REP9(M, P)  M(P,0) M(P,1) M(P,2) M(P,3) M(P,4) M(P,5) M(P,6) M(P,7) M(P,8)
#define DECLQ(P, i) float P##i##x, P##i##y, P##i##z, P##i##w;
#define LOADQ(P, i) { float4 _t = wp[i]; P##i##x = _t.x; P##i##y = _t.y; P##i##z = _t.z; P##i##w = _t.w; }
#define PINQ(P, i)  asm volatile("" : "+v"(P##i##x), "+v"(P##i##y), "+v"(P##i##z), "+v"(P##i##w));
#define FMAQ(P, i)                                                        \
    {  float4 hv = *(const float4*)&hb[(i) * 4];                          \
       z0 = fmaf(P##i##x, hv.x, z0); z1 = fmaf(P##i##y, hv.y, z1);        \
       z2 = fmaf(P##i##z, hv.z, z2); z3 = fmaf(P##i##w, hv.w, z3); }

// array-based dots (fallback kernel only)
#define DOT36(W, H, Z0, Z1, Z2, Z3)                        \
    do {                                                   \
        _Pragma("unroll") for (int _k = 0; _k < 9; ++_k) { \
            float4 hv = *(const float4*)&(H)[_k * 4];      \
            Z0 = fmaf((W)[_k * 4 + 0], hv.x, Z0);          \
            Z1 = fmaf((W)[_k * 4 + 1], hv.y, Z1);          \
            Z2 = fmaf((W)[_k * 4 + 2], hv.z, Z2);          \
            Z3 = fmaf((W)[_k * 4 + 3], hv.w, Z3);          \
        }                                                  \
    } while (0)

#define DOT72(W, H, Z0, Z1, Z2, Z3)                         \
    do {                                                    \
        _Pragma("unroll") for (int _k = 0; _k < 18; ++_k) { \
            float4 hv = *(const float4*)&(H)[_k * 4];       \
            Z0 = fmaf((W)[_k * 4 + 0], hv.x, Z0);           \
            Z1 = fmaf((W)[_k * 4 + 1], hv.y, Z1);           \
            Z2 = fmaf((W)[_k * 4 + 2], hv.z, Z2);           \
            Z3 = fmaf((W)[_k * 4 + 3], hv.w, Z3);           \
        }                                                   \
    } while (0)

// ============ K1: layer-0 REVERSE scan, full batch -> h0r (151 MB ws) ========
#define SG1 4
#define NTK1 (SG1 * G4)   // 576
__global__ __launch_bounds__(NTK1) void l0rev_kernel(
    const float* __restrict__ x,
    const float* __restrict__ Wih, const float* __restrict__ Whh,
    const float* __restrict__ bih, const float* __restrict__ bhh,
    float* __restrict__ h0r)
{
    const int tid = threadIdx.x;
    const int cc  = tid / G4;
    const int g   = tid % G4;
    const int b   = blockIdx.x * SG1 + cc;

    __shared__ float xs[SG1][TT];
    __shared__ float hs[SG1][40];
    __shared__ float zs[SG1][G4];

    for (int i = g; i < TT; i += G4) xs[cc][i] = x[(size_t)b * TT + i];

    REP9(DECLQ, R)
    {
        const float4* wp = (const float4*)(Whh + g * Hn);
        REP9(LOADQ, R)
    }
    float wx   = Wih[g];
    float bias = bih[g] + bhh[g];
    REP9(PINQ, R)
    asm volatile("" : "+v"(wx), "+v"(bias));

    if (g < 40) hs[cc][g] = 0.0f;
    float c = 0.0f;
    __syncthreads();

    float* dst = h0r + (size_t)b * TT * Hn;

    for (int s = 0; s < TT; ++s) {
        const int t = TT - 1 - s;
        float z0 = fmaf(xs[cc][t], wx, bias), z1 = 0.f, z2 = 0.f, z3 = 0.f;
        {
            const float* hb = hs[cc];
            REP9(FMAQ, R)
        }
        zs[cc][g] = (z0 + z1) + (z2 + z3);
        __syncthreads();
        if (g < Hn) {
            float zi = zs[cc][g], zf = zs[cc][g + 36], zg = zs[cc][g + 72], zo = zs[cc][g + 108];
            c = sigf(zf) * c + sigf(zi) * tanh_fast(zg);
            float h = sigf(zo) * tanh_fast(c);
            hs[cc][g] = h;
            dst[(size_t)t * Hn + g] = h;
        }
        __syncthreads();
    }
}

// ====== K2: cohort-pipelined skewed fusion, 8 chains/block (A:0-3, B:4-7) ====
// Phase = { combine+stage one cohort  ||  full dot of the other } + 1 barrier.
// Dot groups: 0:Whh0f.h0f(+x)  1:Wih1f[:, :36].h0f  2:Wih1f[:, 36:].h0r  3:Whh1f.h1
#define SG2  8
#define NT2  576
#define NB2  (BB / SG2)   // 256 blocks

__global__ __launch_bounds__(NT2) void fused_fl_kernel(
    const float* __restrict__ x,
    const float* __restrict__ Wih0f, const float* __restrict__ Whh0f,
    const float* __restrict__ bih0f, const float* __restrict__ bhh0f,
    const float* __restrict__ Wih1f, const float* __restrict__ Whh1f,
    const float* __restrict__ bih1f, const float* __restrict__ bhh1f,
    const float* __restrict__ Wih1r,
    const float* __restrict__ bih1r, const float* __restrict__ bhh1r,
    const float* __restrict__ fcW, const float* __restrict__ fcb,
    const float* __restrict__ h0r,
    float* __restrict__ out)
{
    const int tid  = threadIdx.x;
    const int gp   = tid / G4;           // dot group 0..3
    const int g    = tid % G4;           // gate row
    const int base = blockIdx.x * SG2;
    // combine roles
    const int cA = (tid < 144) ? tid / 36 : 0;               // L0-combine chain
    const int uA = (tid < 144) ? tid % 36 : 0;
    const int cB = (tid >= 144 && tid < 288) ? (tid - 144) / 36 : 0;   // L1-combine
    const int uB = (tid >= 144 && tid < 288) ? (tid - 144) % 36 : 0;
    const int cs = (tid >= 288 && tid < 432) ? (tid - 288) / 36 : 0;   // staging
    const int us = (tid >= 288 && tid < 432) ? (tid - 288) % 36 : 0;

    __shared__ float4 wt0t[9 * G4];      // Whh0f transposed (20.7 KB)
    __shared__ float4 wt1t[18 * G4];     // Wih1f transposed (41.5 KB)
    __shared__ float4 wt3t[9 * G4];      // Whh1f transposed (20.7 KB)
    __shared__ float xs[SG2][TT + 2];    // 16.4 KB
    __shared__ float h0f[SG2][40];       // single-buffered (cohort-disjoint phases)
    __shared__ float h0rs[SG2][40];
    __shared__ float h1s[SG2][40];
    __shared__ float zF[SG2][G4];        // 4.6 KB
    __shared__ float zL[3][SG2][G4];     // 13.8 KB
    __shared__ float red[SG2][Hn];

    // ---------------- one-time staging ----------------
    for (int i = tid; i < 9 * G4; i += NT2) {
        int q = i / G4, r = i % G4;
        wt0t[q * G4 + r] = ((const float4*)(Whh0f + r * Hn))[q];
        wt3t[q * G4 + r] = ((const float4*)(Whh1f + r * Hn))[q];
    }
    for (int i = tid; i < 18 * G4; i += NT2) {
        int q = i / G4, r = i % G4;
        wt1t[q * G4 + r] = ((const float4*)(Wih1f + r * 72))[q];
    }
    for (int i = tid; i < SG2 * (TT + 2); i += NT2) {
        int c = i / (TT + 2), t = i % (TT + 2);
        xs[c][t] = (t < TT) ? x[(size_t)(base + c) * TT + t] : 0.0f;
    }
    for (int i = tid; i < SG2 * 40; i += NT2) {
        (&h0f[0][0])[i] = 0.0f;
        (&h0rs[0][0])[i] = 0.0f;
        (&h1s[0][0])[i] = 0.0f;
    }

    const float4* wb4 = (gp == 0) ? wt0t
                      : (gp == 1) ? wt1t
                      : (gp == 2) ? (wt1t + 9 * G4)
                                  : wt3t;
    const float wx0  = (gp == 0) ? Wih0f[g] : 0.0f;
    const float bsum = (gp == 0) ? (bih0f[g] + bhh0f[g])
                     : (gp == 3) ? (bih1f[g] + bhh1f[g]) : 0.0f;

    const float* srowA = h0r + (size_t)(base + cs) * TT * Hn + us;
    const float* srowB = h0r + (size_t)(base + 4 + cs) * TT * Hn + us;
    float c0A = 0.f, c0B = 0.f, c1A = 0.f, c1B = 0.f, rvA = 0.f, rvB = 0.f;
    __syncthreads();

    // ---- prologue: zF(x-only, h=0) for all 8 chains; stage h0r(0); prefetch h0r(1)
    if (gp == 0) {
#pragma unroll
        for (int ci = 0; ci < SG2; ++ci)
            zF[ci][g] = fmaf(xs[ci][0], wx0, bsum);
    }
    if (tid >= 288 && tid < 432) {
        h0rs[cs][us]     = srowA[0];
        h0rs[4 + cs][us] = srowB[0];
        rvA = srowA[Hn];
        rvB = srowB[Hn];
    }
    __syncthreads();
    if (tid < 144) {    // h0f(0) both cohorts (c=0 start: forget term vanishes)
        {   float zi = zF[cA][uA], zg = zF[cA][uA + 72], zo = zF[cA][uA + 108];
            c0A = sigf(zi) * tanh_fast(zg);
            h0f[cA][uA] = sigf(zo) * tanh_fast(c0A); }
        {   float zi = zF[4 + cA][uA], zg = zF[4 + cA][uA + 72], zo = zF[4 + cA][uA + 108];
            c0B = sigf(zi) * tanh_fast(zg);
            h0f[4 + cA][uA] = sigf(zo) * tanh_fast(c0B); }
    }
    __syncthreads();

// full dot for cohort starting at chain CH0 (writes z slices of that cohort)
#define DOT_PHASE(CH0)                                                        \
    {   const float* hbb = (gp <= 1) ? &h0f[CH0][0]                           \
                         : (gp == 2) ? &h0rs[CH0][0] : &h1s[CH0][0];          \
        float A0, B0, C0, D0;                                                 \
        if (gp == 0) {                                                        \
            A0 = fmaf(xs[CH0 + 0][t + 1], wx0, bsum);                         \
            B0 = fmaf(xs[CH0 + 1][t + 1], wx0, bsum);                         \
            C0 = fmaf(xs[CH0 + 2][t + 1], wx0, bsum);                         \
            D0 = fmaf(xs[CH0 + 3][t + 1], wx0, bsum);                         \
        } else { A0 = bsum; B0 = bsum; C0 = bsum; D0 = bsum; }                \
        float A1 = 0.f, A2 = 0.f, A3 = 0.f, B1 = 0.f, B2 = 0.f, B3 = 0.f;     \
        float C1 = 0.f, C2 = 0.f, C3 = 0.f, D1 = 0.f, D2 = 0.f, D3 = 0.f;     \
        _Pragma("unroll")                                                     \
        for (int i = 0; i < 9; ++i) {                                         \
            float4 w = wb4[i * G4 + g];                                       \
            float4 h;                                                         \
            h = *(const float4*)&hbb[0 * 40 + i * 4];                         \
            A0 = fmaf(w.x, h.x, A0); A1 = fmaf(w.y, h.y, A1);                 \
            A2 = fmaf(w.z, h.z, A2); A3 = fmaf(w.w, h.w, A3);                 \
            h = *(const float4*)&hbb[1 * 40 + i * 4];                         \
            B0 = fmaf(w.x, h.x, B0); B1 = fmaf(w.y, h.y, B1);                 \
            B2 = fmaf(w.z, h.z, B2); B3 = fmaf(w.w, h.w, B3);                 \
            h = *(const float4*)&hbb[2 * 40 + i * 4];                         \
            C0 = fmaf(w.x, h.x, C0); C1 = fmaf(w.y, h.y, C1);                 \
            C2 = fmaf(w.z, h.z, C2); C3 = fmaf(w.w, h.w, C3);                 \
            h = *(const float4*)&hbb[3 * 40 + i * 4];                         \
            D0 = fmaf(w.x, h.x, D0); D1 = fmaf(w.y, h.y, D1);                 \
            D2 = fmaf(w.z, h.z, D2); D3 = fmaf(w.w, h.w, D3);                 \
        }                                                                     \
        float* zt = (gp == 0) ? &zF[CH0][0] : &zL[gp - 1][CH0][0];            \
        zt[0 * G4 + g] = (A0 + A1) + (A2 + A3);                               \
        zt[1 * G4 + g] = (B0 + B1) + (B2 + B3);                               \
        zt[2 * G4 + g] = (C0 + C1) + (C2 + C3);                               \
        zt[3 * G4 + g] = (D0 + D1) + (D2 + D3);                               \
    }

#define L0_COMBINE(CH0, CREG, WRITE_H)                                        \
    {   float zi = zF[(CH0) + cA][uA],       zf = zF[(CH0) + cA][uA + 36];    \
        float zg = zF[(CH0) + cA][uA + 72],  zo = zF[(CH0) + cA][uA + 108];   \
        CREG = sigf(zf) * CREG + sigf(zi) * tanh_fast(zg);                    \
        if (WRITE_H) h0f[(CH0) + cA][uA] = sigf(zo) * tanh_fast(CREG);        \
    }

#define L1_COMBINE(CH0, CREG)                                                 \
    {   float zi = zL[0][(CH0) + cB][uB]       + zL[1][(CH0) + cB][uB]       + zL[2][(CH0) + cB][uB];       \
        float zf = zL[0][(CH0) + cB][uB + 36]  + zL[1][(CH0) + cB][uB + 36]  + zL[2][(CH0) + cB][uB + 36];  \
        float zg = zL[0][(CH0) + cB][uB + 72]  + zL[1][(CH0) + cB][uB + 72]  + zL[2][(CH0) + cB][uB + 72];  \
        float zo = zL[0][(CH0) + cB][uB + 108] + zL[1][(CH0) + cB][uB + 108] + zL[2][(CH0) + cB][uB + 108]; \
        CREG = sigf(zf) * CREG + sigf(zi) * tanh_fast(zg);                    \
        h1s[(CH0) + cB][uB] = sigf(zo) * tanh_fast(CREG);                     \
    }

    for (int t = 0; t < TT; ++t) {
        // ---- P1: combine_B(t-1) + stage h0r_B(t)  ||  dot_A(t) ----
        if (t > 0) {
            if (tid < 144) {
                L0_COMBINE(4, c0B, true)            // h0f_B(t)
            } else if (tid < 288) {
                L1_COMBINE(4, c1B)                  // h1_B(t-1)
            } else if (tid < 432) {
                h0rs[4 + cs][us] = rvB;             // h0r_B(t)
                rvB = (t + 1 < TT) ? srowB[(size_t)(t + 1) * Hn] : 0.0f;
            }
        }
        DOT_PHASE(0)
        __syncthreads();

        // ---- P2: combine_A(t) + stage h0r_A(t+1)  ||  dot_B(t) ----
        if (tid < 144) {
            L0_COMBINE(0, c0A, (t + 1 < TT))        // h0f_A(t+1), keep h0f_A(TT-1)
        } else if (tid < 288) {
            L1_COMBINE(0, c1A)                      // h1_A(t)
        } else if (tid < 432) {
            if (t + 1 < TT) h0rs[cs][us] = rvA;     // h0r_A(t+1), keep h0r_A(TT-1)
            rvA = (t + 2 < TT) ? srowA[(size_t)(t + 2) * Hn] : 0.0f;
        }
        DOT_PHASE(4)
        __syncthreads();
    }
    // epilogue: combine_B(TT-1) — L1 part only (h1_B(TT-1)); h0f_B stays at TT-1
    if (tid >= 144 && tid < 288) {
        L1_COMBINE(4, c1B)
    }
    __syncthreads();

    // ---- tail: L1 reverse single step at t=TT-1 (h0=c0=0) + FC ----
    {
        const int gpT = tid / G4, gT = tid % G4;
#pragma unroll
        for (int s2 = 0; s2 < 2; ++s2) {
            const int cc = gpT * 2 + s2;
            float zR = bih1r[gT] + bhh1r[gT];
            const float* wrq = Wih1r + gT * 72;
#pragma unroll
            for (int k = 0; k < Hn; ++k) zR = fmaf(wrq[k],      h0f[cc][k],  zR);
#pragma unroll
            for (int k = 0; k < Hn; ++k) zR = fmaf(wrq[36 + k], h0rs[cc][k], zR);
            zF[cc][gT] = zR;
        }
    }
    __syncthreads();
    if (tid < 288) {
        const int c2 = tid / 36, i2 = tid % 36;
        float zi = zF[c2][i2], zg = zF[c2][i2 + 72], zo = zF[c2][i2 + 108];
        float cR = sigf(zi) * tanh_fast(zg);   // c0=0: forget term vanishes
        float hR = sigf(zo) * tanh_fast(cR);
        red[c2][i2] = fcW[36 + i2] * hR + fcW[i2] * h1s[c2][i2];
    }
    __syncthreads();
    if (tid < SG2) {
        float s2 = fcb[0];
        for (int j = 0; j < Hn; ++j) s2 += red[tid][j];
        out[base + tid] = s2;
    }
#undef DOT_PHASE
#undef L0_COMBINE
#undef L1_COMBINE
}

// ================= FALLBACK PATH (zero workspace, ckpt/recompute) ============
__global__ __launch_bounds__(G4, 1) void fused_all_kernel(
    const float* __restrict__ x,
    const float* __restrict__ Wih0f, const float* __restrict__ Whh0f,
    const float* __restrict__ bih0f, const float* __restrict__ bhh0f,
    const float* __restrict__ Wih0r, const float* __restrict__ Whh0r,
    const float* __restrict__ bih0r, const float* __restrict__ bhh0r,
    const float* __restrict__ Wih1f, const float* __restrict__ Whh1f,
    const float* __restrict__ bih1f, const float* __restrict__ bhh1f,
    const float* __restrict__ Wih1r,
    const float* __restrict__ bih1r, const float* __restrict__ bhh1r,
    const float* __restrict__ fcW, const float* __restrict__ fcb,
    float* __restrict__ out)
{
    const int g = threadIdx.x;
    const int b = blockIdx.x;

    __shared__ float xs[TT];
    __shared__ float cbuf[64][Hn];
    __shared__ float ckpt_h[8][Hn], ckpt_c[8][Hn];
    __shared__ float hr[40], h0s[80], hs1[40], zs[G4], red[40];

    for (int i = g; i < TT; i += G4) xs[i] = x[(size_t)b * TT + i];

    float wr[Hn], wf[Hn];
#pragma unroll
    for (int k = 0; k < Hn; ++k) wr[k] = Whh0r[g * Hn + k];
#pragma unroll
    for (int k = 0; k < Hn; ++k) wf[k] = Whh0f[g * Hn + k];
    const float wxr = Wih0r[g], br = bih0r[g] + bhh0r[g];
    const float wxf = Wih0f[g], bf = bih0f[g] + bhh0f[g];
    float w1i[72];
#pragma unroll
    for (int k = 0; k < 72; ++k) w1i[k] = Wih1f[g * 72 + k];
    float w1h[Hn];
#pragma unroll
    for (int k = 0; k < Hn; ++k) w1h[k] = Whh1f[g * Hn + k];
    const float b1 = bih1f[g] + bhh1f[g];

    if (g < Hn) hr[g] = 0.0f;
    float cr = 0.0f;
    __syncthreads();
    for (int s = 0; s < TT; ++s) {
        const int t = TT - 1 - s;
        if ((t & 63) == 63 && g < Hn) { ckpt_h[t >> 6][g] = hr[g]; ckpt_c[t >> 6][g] = cr; }
        float z0 = fmaf(xs[t], wxr, br), z1 = 0.f, z2 = 0.f, z3 = 0.f;
        DOT36(wr, hr, z0, z1, z2, z3);
        zs[g] = (z0 + z1) + (z2 + z3);
        __syncthreads();
        if (g < Hn) {
            float zi = zs[g], zf = zs[g + 36], zg = zs[g + 72], zo = zs[g + 108];
            cr = sigf(zf) * cr + sigf(zi) * tanh_fast(zg);
            hr[g] = sigf(zo) * tanh_fast(cr);
        }
        __syncthreads();
    }

    if (g < Hn) { h0s[g] = 0.0f; hs1[g] = 0.0f; }
    float c0 = 0.0f, c1 = 0.0f;
    __syncthreads();

    for (int m = 0; m < 8; ++m) {
        if (g < Hn) { hr[g] = ckpt_h[m][g]; cr = ckpt_c[m][g]; }
        __syncthreads();
        for (int j = 0; j < 64; ++j) {
            const int t = m * 64 + 63 - j;
            float z0 = fmaf(xs[t], wxr, br), z1 = 0.f, z2 = 0.f, z3 = 0.f;
            DOT36(wr, hr, z0, z1, z2, z3);
            zs[g] = (z0 + z1) + (z2 + z3);
            __syncthreads();
            if (g < Hn) {
                float zi = zs[g], zf = zs[g + 36], zg = zs[g + 72], zo = zs[g + 108];
                cr = sigf(zf) * cr + sigf(zi) * tanh_fast(zg);
                float h = sigf(zo) * tanh_fast(cr);
                hr[g] = h;
                cbuf[t & 63][g] = h;
            }
            __syncthreads();
        }
        for (int j = 0; j < 64; ++j) {
            const int t = m * 64 + j;
            float z0 = fmaf(xs[t], wxf, bf), z1 = 0.f, z2 = 0.f, z3 = 0.f;
            DOT36(wf, h0s, z0, z1, z2, z3);
            zs[g] = (z0 + z1) + (z2 + z3);
            __syncthreads();
            if (g < Hn) {
                float zi = zs[g], zf = zs[g + 36], zg = zs[g + 72], zo = zs[g + 108];
                c0 = sigf(zf) * c0 + sigf(zi) * tanh_fast(zg);
                h0s[g] = sigf(zo) * tanh_fast(c0);
            } else if (g < 72) {
                h0s[g] = cbuf[j][g - 36];
            }
            __syncthreads();
            float y0 = b1, y1 = 0.f, y2 = 0.f, y3 = 0.f;
            DOT72(w1i, h0s, y0, y1, y2, y3);
            DOT36(w1h, hs1, y0, y1, y2, y3);
            zs[g] = (y0 + y1) + (y2 + y3);
            __syncthreads();
            if (g < Hn) {
                float zi = zs[g], zf = zs[g + 36], zg = zs[g + 72], zo = zs[g + 108];
                c1 = sigf(zf) * c1 + sigf(zi) * tanh_fast(zg);
                hs1[g] = sigf(zo) * tanh_fast(c1);
            }
            __syncthreads();
        }
    }

    float zR = bih1r[g] + bhh1r[g];
#pragma unroll
    for (int k = 0; k < 72; ++k) zR = fmaf(Wih1r[g * 72 + k], h0s[k], zR);
    zs[g] = zR;
    __syncthreads();
    if (g < Hn) {
        float zi = zs[g], zg = zs[g + 72], zo = zs[g + 108];
        float c  = sigf(zi) * tanh_fast(zg);
        float hrv = sigf(zo) * tanh_fast(c);
        red[g] = fcW[36 + g] * hrv + fcW[g] * hs1[g];
    }
    __syncthreads();
    if (g == 0) {
        float s = fcb[0];
        for (int j = 0; j < Hn; ++j) s += red[j];
        out[b] = s;
    }
}

extern "C" void kernel_launch(void* const* d_in, const int* in_sizes, int n_in,
                              void* d_out, int out_size, void* d_ws, size_t ws_size,
                              hipStream_t stream)
{
    const float* x     = (const float*)d_in[0];
    const float* Wih0f = (const float*)d_in[1];
    const float* Whh0f = (const float*)d_in[2];
    const float* bih0f = (const float*)d_in[3];
    const float* bhh0f = (const float*)d_in[4];
    const float* Wih0r = (const float*)d_in[5];
    const float* Whh0r = (const float*)d_in[6];
    const float* bih0r = (const float*)d_in[7];
    const float* bhh0r = (const float*)d_in[8];
    const float* Wih1f = (const float*)d_in[9];
    const float* Whh1f = (const float*)d_in[10];
    const float* bih1f = (const float*)d_in[11];
    const float* bhh1f = (const float*)d_in[12];
    const float* Wih1r = (const float*)d_in[13];
    const float* bih1r = (const float*)d_in[15];
    const float* bhh1r = (const float*)d_in[16];
    const float* fcW   = (const float*)d_in[17];
    const float* fcb   = (const float*)d_in[18];

    const size_t need = (size_t)BB * TT * Hn * sizeof(float);   // 151 MB (known-safe)
    if (d_ws != nullptr && ws_size >= need) {
        float* h0r = (float*)d_ws;
        l0rev_kernel<<<BB / SG1, NTK1, 0, stream>>>(x, Wih0r, Whh0r, bih0r, bhh0r, h0r);
        fused_fl_kernel<<<NB2, NT2, 0, stream>>>(
            x, Wih0f, Whh0f, bih0f, bhh0f, Wih1f, Whh1f, bih1f, bhh1f,
            Wih1r, bih1r, bhh1r, fcW, fcb, h0r, (float*)d_out);
    } else {
        fused_all_kernel<<<BB, G4, 0, stream>>>(
            x, Wih0f, Whh0f, bih0f, bhh0f, Wih0r, Whh0r, bih0r, bhh0r,
            Wih1f, Whh1f, bih1f, bhh1f, Wih1r, bih1r, bhh1r, fcW, fcb,
            (float*)d_out);
    }
}